// Round 11
// baseline (91.202 us; speedup 1.0000x reference)
//
#include <hip/hip_runtime.h>
#include <hip/hip_bf16.h>

#define BATCH 4096
#define NH    1024
#define KCAT  2048   // x(1024) | h(1024)
#define NJ    4096   // 4 gates * 1024
#define NT    (KCAT / 64)   // 32 K-tiles

typedef __bf16 bf16x8 __attribute__((ext_vector_type(8)));
typedef float  f32x16 __attribute__((ext_vector_type(16)));
typedef unsigned short u16x8 __attribute__((ext_vector_type(8)));

struct WPtrs { const float* wx[4]; const float* wh[4]; };
struct BPtrs { const float* bx[4]; const float* bh[4]; };

__device__ __forceinline__ unsigned short f2b(float f) {
  union { float f; unsigned u; } v; v.f = f;
  return (unsigned short)((v.u + 0x7fffu + ((v.u >> 16) & 1u)) >> 16);  // RNE
}

__device__ __forceinline__ void gload_lds16(const void* g, void* l) {
  __builtin_amdgcn_global_load_lds(
      (const __attribute__((address_space(1))) unsigned int*)g,
      (__attribute__((address_space(3))) unsigned int*)l, 16, 0, 0);
}

__device__ __forceinline__ float sigmoid_f(float x) {
  x = fminf(fmaxf(x, -30.f), 30.f);
  return 1.f / (1.f + __expf(-x));
}
__device__ __forceinline__ float tanh_f(float x) {
  x = fminf(fmaxf(x, -15.f), 15.f);
  float e = __expf(2.f * x);
  return (e - 1.f) / (e + 1.f);
}

// ---------------- fused pack kernel (A-cat, B-cat, bias in one launch) -----
__global__ __launch_bounds__(256) void pack_all(
    const float* __restrict__ x, const float* __restrict__ h,
    WPtrs W, BPtrs B,
    __hip_bfloat16* __restrict__ Acat, __hip_bfloat16* __restrict__ Bcat,
    float* __restrict__ biasc) {
  int bid = blockIdx.x;
  if (bid < 4096) {            // A_cat: [row][k], k<1024 -> x, else h
    int t = bid * 256 + threadIdx.x;
    int base = t * 8;
    int row = base >> 11;
    int k   = base & 2047;
    const float* src = (k < 1024) ? (x + (size_t)row * 1024 + k)
                                  : (h + (size_t)row * 1024 + (k - 1024));
    float4 v0 = ((const float4*)src)[0];
    float4 v1 = ((const float4*)src)[1];
    u16x8 o;
    o[0]=f2b(v0.x); o[1]=f2b(v0.y); o[2]=f2b(v0.z); o[3]=f2b(v0.w);
    o[4]=f2b(v1.x); o[5]=f2b(v1.y); o[6]=f2b(v1.z); o[7]=f2b(v1.w);
    *(u16x8*)((unsigned short*)Acat + base) = o;
  } else if (bid < 8192) {     // B_cat: j = (n>>5)*128 + g*32 + (n&31)
    int t = (bid - 4096) * 256 + threadIdx.x;
    int base = t * 8;
    int j = base >> 11;
    int k = base & 2047;
    int n = ((j >> 7) << 5) + (j & 31);
    int g = (j >> 5) & 3;
    const float* src = (k < 1024) ? (W.wx[g] + (size_t)n * 1024 + k)
                                  : (W.wh[g] + (size_t)n * 1024 + (k - 1024));
    float4 v0 = ((const float4*)src)[0];
    float4 v1 = ((const float4*)src)[1];
    u16x8 o;
    o[0]=f2b(v0.x); o[1]=f2b(v0.y); o[2]=f2b(v0.z); o[3]=f2b(v0.w);
    o[4]=f2b(v1.x); o[5]=f2b(v1.y); o[6]=f2b(v1.z); o[7]=f2b(v1.w);
    *(u16x8*)((unsigned short*)Bcat + base) = o;
  } else {                     // bias: biasc[g*1024+n] = bx[g][n]+bh[g][n]
    int i = (bid - 8192) * 256 + threadIdx.x;   // 0..4095
    int g = i >> 10, n = i & 1023;
    biasc[i] = B.bx[g][n] + B.bh[g][n];
  }
}

// ---- 256x256 WAR-pipelined GEMM, 32x32x16 MFMA, + in-lane LSTM epilogue ----
// vs r8: MFMA shape 16x16x32 -> 32x32x16 (+15-20% pipe rate per m119, half
// the MFMA instruction count). Wave geometry 4M x 2N (per-wave 64x128), so a
// wave's 128 j-cols = 4 x 32-col gate tiles -> gates f,i,o,c at the SAME
// lane&31 position in acc[mt][0..3] (in-lane fusion preserved via new B pack).
// Schedule = r8's 4-window WAR pipeline, K-windowed (window = one K=16 step):
//   hold all 8 A-frags per tile (read once at W1), ping-pong B (4 frags/set).
//   A region free after W1 -> A(t+2) staged W3/W4 (curo); B(t+1) staged
//   W1/W2 (nxto, dead since t-1). Steady in-flight at W4 = 12; vmcnt(4)
//   retires exactly A(t+1)+B(t+1) = what W4's next-tile reads need.
// Swizzle & staging identical to r8 (0 conflicts); new read pattern audited
// at <=2 lanes/bank (free per m136).

#define STAGE_A_HALF(T, H)                                                      \
  {                                                                             \
    _Pragma("unroll")                                                           \
    for (int i_ = 0; i_ < 2; ++i_) {                                            \
      gload_lds16(Ag + (size_t)((H)*128 + i_*64 + strow) * KCAT + (T)*64 +      \
                      stchnk * 8,                                               \
                  &smem[((T)&1)*32768 + (H)*8192 + i_*4096 + w*512]);           \
    }                                                                           \
  }
#define STAGE_B_HALF(T, H)                                                      \
  {                                                                             \
    _Pragma("unroll")                                                           \
    for (int i_ = 0; i_ < 2; ++i_) {                                            \
      gload_lds16(Bg + (size_t)((H)*128 + i_*64 + strow) * KCAT + (T)*64 +      \
                      stchnk * 8,                                               \
                  &smem[((T)&1)*32768 + 16384 + (H)*8192 + i_*4096 + w*512]);   \
    }                                                                           \
  }

// chunk byte offset within a 128B row for K-step KS (16 k = 32B = 2 chunks)
#define CHB(KS) ((((KS)*2 + klh) << 4) ^ sxa)

#define READ_AK(BUFO, KS)                                                       \
  {                                                                             \
    afk[KS][0] = *(const bf16x8*)(smc + (BUFO) + arow0 + CHB(KS));              \
    afk[KS][1] = *(const bf16x8*)(smc + (BUFO) + arow0 + 4096 + CHB(KS));       \
  }
#define READ_BK(BUFO, KS, DST)                                                  \
  {                                                                             \
    _Pragma("unroll")                                                           \
    for (int nt_ = 0; nt_ < 4; ++nt_)                                           \
      DST[nt_] = *(const bf16x8*)(smc + (BUFO) + brow0 + nt_*4096 + CHB(KS));   \
  }
#define MFMA_K(KS, BSET)                                                        \
  {                                                                             \
    _Pragma("unroll")                                                           \
    for (int mt_ = 0; mt_ < 2; ++mt_)                                           \
      _Pragma("unroll")                                                         \
      for (int nt_ = 0; nt_ < 4; ++nt_)                                         \
        acc[mt_][nt_] = __builtin_amdgcn_mfma_f32_32x32x16_bf16(                \
            afk[KS][mt_], BSET[nt_], acc[mt_][nt_], 0, 0, 0);                   \
  }

#define BAR    __builtin_amdgcn_s_barrier()
#define PRIO1  __builtin_amdgcn_s_setprio(1)
#define PRIO0  __builtin_amdgcn_s_setprio(0)

__global__ __launch_bounds__(512, 2) void lstm_gemm8(
    const unsigned short* __restrict__ Acat,
    const unsigned short* __restrict__ Bcat,
    const float* __restrict__ biasc,
    const float* __restrict__ cell,
    float* __restrict__ outH, float* __restrict__ outC) {
  __shared__ unsigned short smem[65536];  // 128 KiB

  const int tid  = threadIdx.x;
  const int w    = tid >> 6;    // 0..7
  const int lane = tid & 63;
  const int wr   = w >> 1;      // 0..3 (M quarter: 64 rows)
  const int wc   = w & 1;       // 0..1 (N half: 128 j-cols)
  const int l31  = lane & 31;
  const int klh  = lane >> 5;            // k-half selector
  const int sxa  = (lane & 7) << 4;      // swizzle XOR ((row&7)<<4, row&7==lane&7)

  // XCD-aware bijective swizzle (256 blocks, 8 XCDs)
  const int bid = blockIdx.x;
  const int s   = (bid & 7) * 32 + (bid >> 3);
  const int bx  = s & 15;
  const int by  = s >> 4;

  const unsigned short* Ag = Acat + (size_t)(by * 256) * KCAT;
  const unsigned short* Bg = Bcat + (size_t)(bx * 256) * KCAT;

  // staging source mapping (pre-swizzled global chunk) — identical to r8
  const int strow  = w * 8 + (lane >> 3);
  const int stchnk = (lane & 7) ^ ((lane >> 3) & 7);

  // per-thread read base byte offsets into smem
  const int arow0 = (wr * 64 + l31) * 128;           // + mt*4096 + CHB
  const int brow0 = 32768 + (wc * 128 + l31) * 128;  // + nt*4096 + CHB
  const char* smc = (const char*)smem;

  f32x16 acc[2][4] = {};
  bf16x8 afk[4][2];   // all A-frags of current tile [ks][mt]
  bf16x8 bf0[4];      // B frag set 0 [nt] (one K-step)
  bf16x8 bf1[4];      // B frag set 1

  // prologue: A(0), B(0), A(1); retire A(0)+B(0), leave A(1) in flight
  STAGE_A_HALF(0, 0);
  STAGE_A_HALF(0, 1);
  STAGE_B_HALF(0, 0);
  STAGE_B_HALF(0, 1);
  STAGE_A_HALF(1, 0);
  STAGE_A_HALF(1, 1);
  asm volatile("s_waitcnt vmcnt(4)" ::: "memory");
  BAR;
  READ_AK(0, 0);
  READ_BK(0, 0, bf0);

  for (int t = 0; t < NT; ++t) {
    const int curo = (t & 1) * 65536;
    const int nxto = curo ^ 65536;
    const bool s1 = (t + 1 < NT);
    const bool s2 = (t + 2 < NT);

    // W1: MFMA ks0 | read A ks1-3 + B ks1
    BAR;
    if (s1) STAGE_B_HALF(t + 1, 0);
    PRIO1; MFMA_K(0, bf0); PRIO0;
    READ_AK(curo, 1);
    READ_BK(curo, 1, bf1);
    READ_AK(curo, 2);
    READ_AK(curo, 3);
    // W2: MFMA ks1 | read B ks2 (WAR over bf0)
    BAR;
    if (s1) STAGE_B_HALF(t + 1, 1);
    PRIO1; MFMA_K(1, bf1); PRIO0;
    READ_BK(curo, 2, bf0);
    // W3: MFMA ks2 | read B ks3 (A region of curo free since W1)
    BAR;
    if (s2) STAGE_A_HALF(t + 2, 0);
    PRIO1; MFMA_K(2, bf0); PRIO0;
    READ_BK(curo, 3, bf1);
    // W4: boundary publish | MFMA ks3 | read next-tile A ks0 + B ks0
    if (s2) {
      STAGE_A_HALF(t + 2, 1);
      asm volatile("s_waitcnt vmcnt(4)" ::: "memory");
    } else if (s1) {
      asm volatile("s_waitcnt vmcnt(0)" ::: "memory");
    }
    BAR;
    PRIO1; MFMA_K(3, bf1); PRIO0;
    if (s1) {
      READ_AK(nxto, 0);
      READ_BK(nxto, 0, bf0);
    }
  }

  // ---------------- epilogue: in-lane gate fusion (32x32 C/D layout) -------
  // col = lane&31, row = (reg&3) + 8*(reg>>2) + 4*(lane>>5)  [m74/m101]
  const int nbase = (bx * 2 + wc) * 32 + l31;   // hidden index 0..1023
  const float bfv = biasc[nbase];
  const float biv = biasc[1024 + nbase];
  const float bov = biasc[2048 + nbase];
  const float bcv = biasc[3072 + nbase];
  const int rbase = by * 256 + wr * 64 + 4 * klh;

#pragma unroll
  for (int mt = 0; mt < 2; ++mt) {
#pragma unroll
    for (int r = 0; r < 16; ++r) {
      int row = rbase + mt * 32 + (r & 3) + 8 * (r >> 2);
      float pf = acc[mt][0][r] + bfv;
      float pi = acc[mt][1][r] + biv;
      float po = acc[mt][2][r] + bov;
      float pc = acc[mt][3][r] + bcv;
      float fg = sigmoid_f(pf);
      float ig = sigmoid_f(pi);
      float og = sigmoid_f(po);
      float cg = tanh_f(pc);
      float cold = cell[(size_t)row * NH + nbase];
      float cn = fg * cold + ig * cg;
      float hn = og * tanh_f(cn);
      outH[(size_t)row * NH + nbase] = hn;
      outC[(size_t)row * NH + nbase] = cn;
    }
  }
}

extern "C" void kernel_launch(void* const* d_in, const int* in_sizes, int n_in,
                              void* d_out, int out_size, void* d_ws, size_t ws_size,
                              hipStream_t stream) {
  const float* x    = (const float*)d_in[0];
  const float* h    = (const float*)d_in[1];
  const float* cell = (const float*)d_in[2];
  WPtrs wp; BPtrs bp;
  for (int g = 0; g < 4; ++g) {
    wp.wx[g] = (const float*)d_in[3 + 2 * g];
    bp.bx[g] = (const float*)d_in[4 + 2 * g];
    wp.wh[g] = (const float*)d_in[11 + 2 * g];
    bp.bh[g] = (const float*)d_in[12 + 2 * g];
  }

  char* ws = (char*)d_ws;
  __hip_bfloat16* Acat = (__hip_bfloat16*)ws;
  __hip_bfloat16* Bcat = (__hip_bfloat16*)(ws + (size_t)BATCH * KCAT * 2);
  float* biasc = (float*)(ws + (size_t)BATCH * KCAT * 2 + (size_t)NJ * KCAT * 2);

  float* outH = (float*)d_out;
  float* outC = outH + (size_t)BATCH * NH;

  pack_all<<<8208, 256, 0, stream>>>(x, h, wp, bp, Acat, Bcat, biasc);

  lstm_gemm8<<<256, 512, 0, stream>>>((const unsigned short*)Acat,
                                      (const unsigned short*)Bcat,
                                      biasc, cell, outH, outC);
}

// Round 12
// 83.958 us; speedup vs baseline: 1.0863x; 1.0863x over previous
//
#include <hip/hip_runtime.h>
#include <hip/hip_bf16.h>

#define BATCH 4096
#define NH    1024
#define KCAT  2048   // x(1024) | h(1024)
#define NJ    4096   // 4 gates * 1024
#define NT    (KCAT / 64)   // 32 K-tiles

typedef __bf16 bf16x8 __attribute__((ext_vector_type(8)));
typedef float  f32x4  __attribute__((ext_vector_type(4)));
typedef unsigned short u16x8 __attribute__((ext_vector_type(8)));

struct WPtrs { const float* wx[4]; const float* wh[4]; };
struct BPtrs { const float* bx[4]; const float* bh[4]; };

__device__ __forceinline__ unsigned short f2b(float f) {
  union { float f; unsigned u; } v; v.f = f;
  return (unsigned short)((v.u + 0x7fffu + ((v.u >> 16) & 1u)) >> 16);  // RNE
}

__device__ __forceinline__ void gload_lds16(const void* g, void* l) {
  __builtin_amdgcn_global_load_lds(
      (const __attribute__((address_space(1))) unsigned int*)g,
      (__attribute__((address_space(3))) unsigned int*)l, 16, 0, 0);
}

__device__ __forceinline__ float sigmoid_f(float x) {
  x = fminf(fmaxf(x, -30.f), 30.f);
  return 1.f / (1.f + __expf(-x));
}
__device__ __forceinline__ float tanh_f(float x) {
  x = fminf(fmaxf(x, -15.f), 15.f);
  float e = __expf(2.f * x);
  return (e - 1.f) / (e + 1.f);
}

// ---------------- fused pack kernel (A-cat, B-cat, bias in one launch) -----
__global__ __launch_bounds__(256) void pack_all(
    const float* __restrict__ x, const float* __restrict__ h,
    WPtrs W, BPtrs B,
    __hip_bfloat16* __restrict__ Acat, __hip_bfloat16* __restrict__ Bcat,
    float* __restrict__ biasc) {
  int bid = blockIdx.x;
  if (bid < 4096) {            // A_cat: [row][k], k<1024 -> x, else h
    int t = bid * 256 + threadIdx.x;
    int base = t * 8;
    int row = base >> 11;
    int k   = base & 2047;
    const float* src = (k < 1024) ? (x + (size_t)row * 1024 + k)
                                  : (h + (size_t)row * 1024 + (k - 1024));
    float4 v0 = ((const float4*)src)[0];
    float4 v1 = ((const float4*)src)[1];
    u16x8 o;
    o[0]=f2b(v0.x); o[1]=f2b(v0.y); o[2]=f2b(v0.z); o[3]=f2b(v0.w);
    o[4]=f2b(v1.x); o[5]=f2b(v1.y); o[6]=f2b(v1.z); o[7]=f2b(v1.w);
    *(u16x8*)((unsigned short*)Acat + base) = o;
  } else if (bid < 8192) {     // B_cat: j = (n>>4)*64 + g*16 + (n&15)
    int t = (bid - 4096) * 256 + threadIdx.x;
    int base = t * 8;
    int j = base >> 11;
    int k = base & 2047;
    int n = ((j >> 6) << 4) + (j & 15);
    int g = (j >> 4) & 3;
    const float* src = (k < 1024) ? (W.wx[g] + (size_t)n * 1024 + k)
                                  : (W.wh[g] + (size_t)n * 1024 + (k - 1024));
    float4 v0 = ((const float4*)src)[0];
    float4 v1 = ((const float4*)src)[1];
    u16x8 o;
    o[0]=f2b(v0.x); o[1]=f2b(v0.y); o[2]=f2b(v0.z); o[3]=f2b(v0.w);
    o[4]=f2b(v1.x); o[5]=f2b(v1.y); o[6]=f2b(v1.z); o[7]=f2b(v1.w);
    *(u16x8*)((unsigned short*)Bcat + base) = o;
  } else {                     // bias: biasc[g*1024+n] = bx[g][n]+bh[g][n]
    int i = (bid - 8192) * 256 + threadIdx.x;   // 0..4095
    int g = i >> 10, n = i & 1023;
    biasc[i] = B.bx[g][n] + B.bh[g][n];
  }
}

// ------- 256x256 WAR-pipelined GEMM + LSTM epilogue (r8 champion) ----------
// Best measured variant (71.2us GEMM, MfmaUtil 40.5%, 0 bank conflicts).
// Each window: MFMA(Qi) on fragments read ONE window earlier, then ds_reads
// for Q(i+1) (WAR reuse of same fragment registers; reads drain during MFMA
// execution + barrier slack). Compiler value-dep lgkm waits only. 16x16x32
// MFMA shape (conflict-free read geometry: 16 rows x 4 chunk-cols + XOR
// swizzle -> <=2 lanes/bank; 32x32 shape is structurally 4-way-conflicted,
// measured r11). vmcnt(4) at W4 retires exactly A(t+1)+B(t+1).

#define STAGE_A_HALF(T, H)                                                      \
  {                                                                             \
    _Pragma("unroll")                                                           \
    for (int i_ = 0; i_ < 2; ++i_) {                                            \
      gload_lds16(Ag + (size_t)((H)*128 + i_*64 + strow) * KCAT + (T)*64 +      \
                      stchnk * 8,                                               \
                  &smem[((T)&1)*32768 + (H)*8192 + i_*4096 + w*512]);           \
    }                                                                           \
  }
#define STAGE_B_HALF(T, H)                                                      \
  {                                                                             \
    _Pragma("unroll")                                                           \
    for (int i_ = 0; i_ < 2; ++i_) {                                            \
      gload_lds16(Bg + (size_t)((H)*128 + i_*64 + strow) * KCAT + (T)*64 +      \
                      stchnk * 8,                                               \
                  &smem[((T)&1)*32768 + 16384 + (H)*8192 + i_*4096 + w*512]);   \
    }                                                                           \
  }

#define READ_A(BUFO, MQ)                                                        \
  {                                                                             \
    _Pragma("unroll")                                                           \
    for (int mf_ = 0; mf_ < 4; ++mf_) {                                         \
      af[mf_][0] = *(const bf16x8*)(smc + (BUFO) + arow0 +                      \
                                    ((MQ)*4 + mf_)*2048 + colb0);               \
      af[mf_][1] = *(const bf16x8*)(smc + (BUFO) + arow0 +                      \
                                    ((MQ)*4 + mf_)*2048 + colb1);               \
    }                                                                           \
  }
#define READ_B(BUFO, NQ, DST)                                                   \
  {                                                                             \
    _Pragma("unroll")                                                           \
    for (int nf_ = 0; nf_ < 2; ++nf_) {                                         \
      DST[nf_][0] = *(const bf16x8*)(smc + (BUFO) + brow0 +                     \
                                     ((NQ)*2 + nf_)*2048 + colb0);              \
      DST[nf_][1] = *(const bf16x8*)(smc + (BUFO) + brow0 +                     \
                                     ((NQ)*2 + nf_)*2048 + colb1);              \
    }                                                                           \
  }
#define MFMA_Q(MQ, NQ, BSET)                                                    \
  {                                                                             \
    _Pragma("unroll")                                                           \
    for (int ks_ = 0; ks_ < 2; ++ks_)                                           \
      _Pragma("unroll")                                                         \
      for (int mf_ = 0; mf_ < 4; ++mf_)                                         \
        _Pragma("unroll")                                                       \
        for (int nf_ = 0; nf_ < 2; ++nf_)                                       \
          acc[(MQ)*4 + mf_][(NQ)*2 + nf_] =                                     \
              __builtin_amdgcn_mfma_f32_16x16x32_bf16(                          \
                  af[mf_][ks_], BSET[nf_][ks_],                                 \
                  acc[(MQ)*4 + mf_][(NQ)*2 + nf_], 0, 0, 0);                    \
  }

#define BAR    __builtin_amdgcn_s_barrier()
#define PRIO1  __builtin_amdgcn_s_setprio(1)
#define PRIO0  __builtin_amdgcn_s_setprio(0)

__global__ __launch_bounds__(512, 2) void lstm_gemm8(
    const unsigned short* __restrict__ Acat,
    const unsigned short* __restrict__ Bcat,
    const float* __restrict__ biasc,
    const float* __restrict__ cell,
    float* __restrict__ outH, float* __restrict__ outC) {
  __shared__ unsigned short smem[65536];  // 128 KiB

  const int tid  = threadIdx.x;
  const int w    = tid >> 6;    // 0..7
  const int lane = tid & 63;
  const int wr   = w >> 2;      // 0..1 (M)
  const int wc   = w & 3;       // 0..3 (N)
  const int lr   = lane & 15;
  const int cb0  = ((lane >> 4) & 3) * 16;   // 16B chunk within row
  const int sx   = (lr & 7) << 4;            // read-side swizzle XOR

  // XCD-aware bijective swizzle (256 blocks, 8 XCDs)
  const int bid = blockIdx.x;
  const int s   = (bid & 7) * 32 + (bid >> 3);
  const int bx  = s & 15;
  const int by  = s >> 4;

  const unsigned short* Ag = Acat + (size_t)(by * 256) * KCAT;
  const unsigned short* Bg = Bcat + (size_t)(bx * 256) * KCAT;

  // staging source mapping (pre-swizzled global chunk)
  const int strow  = w * 8 + (lane >> 3);              // row within 128-row half
  const int stchnk = (lane & 7) ^ ((lane >> 3) & 7);   // swizzled src chunk

  // per-thread read base byte offsets into smem
  const int arow0 = (wr * 128 + lr) * 128;          // + mp*2048 + colb
  const int brow0 = 32768 + (wc * 64 + lr) * 128;   // + n*2048 + colb
  const int colb0 = cb0 ^ sx;
  const int colb1 = (64 + cb0) ^ sx;
  const char* smc = (const char*)smem;

  f32x4 acc[8][4] = {};
  bf16x8 af[4][2];    // current A-quadrant fragments (WAR-recycled)
  bf16x8 bfr0[2][2];  // B nq=0 fragments (persist across tile)
  bf16x8 bfr1[2][2];  // B nq=1 fragments

  // prologue: A(0), B(0), B(1); retire A(0)+B(0), leave B(1) in flight
  STAGE_A_HALF(0, 0);
  STAGE_A_HALF(0, 1);
  STAGE_B_HALF(0, 0);
  STAGE_B_HALF(0, 1);
  STAGE_B_HALF(1, 0);
  STAGE_B_HALF(1, 1);
  asm volatile("s_waitcnt vmcnt(4)" ::: "memory");
  BAR;
  READ_A(0, 0);          // af   = A(0) mq0
  READ_B(0, 0, bfr0);    // bfr0 = B(0) nq0

  for (int t = 0; t < NT; ++t) {
    const int curo = (t & 1) * 65536;
    const int nxto = curo ^ 65536;
    const bool s1 = (t + 1 < NT);
    const bool s2 = (t + 2 < NT);

    // W1: MFMA (0,0) | read B-nq1
    BAR;
    if (s1) STAGE_A_HALF(t + 1, 0);
    PRIO1; MFMA_Q(0, 0, bfr0); PRIO0;
    READ_B(curo, 1, bfr1);
    // W2: MFMA (0,1) | read A-mq1 (WAR over af)
    BAR;
    if (s1) STAGE_A_HALF(t + 1, 1);
    PRIO1; MFMA_Q(0, 1, bfr1); PRIO0;
    READ_A(curo, 1);
    // W3: MFMA (1,0)
    BAR;
    if (s2) STAGE_B_HALF(t + 2, 0);
    PRIO1; MFMA_Q(1, 0, bfr0); PRIO0;
    // W4: boundary publish | MFMA (1,1) | read next-tile A-mq0, B-nq0
    if (s2) {
      STAGE_B_HALF(t + 2, 1);
      asm volatile("s_waitcnt vmcnt(4)" ::: "memory");
    } else if (s1) {
      asm volatile("s_waitcnt vmcnt(0)" ::: "memory");
    }
    BAR;
    PRIO1; MFMA_Q(1, 1, bfr1); PRIO0;
    if (s1) {
      READ_A(nxto, 0);
      READ_B(nxto, 0, bfr0);
    }
  }

  // ---------------- epilogue: in-lane gate fusion ----------------
  const int n_out = (bx * 4 + wc) * 16 + lr;   // hidden index 0..1023
  const float bfv = biasc[n_out];
  const float biv = biasc[1024 + n_out];
  const float bov = biasc[2048 + n_out];
  const float bcv = biasc[3072 + n_out];
  const int q0 = (lane >> 4) * 4;

#pragma unroll
  for (int m = 0; m < 8; ++m) {
    int row0 = by * 256 + wr * 128 + m * 16 + q0;
#pragma unroll
    for (int q = 0; q < 4; ++q) {
      int row = row0 + q;
      float pf = acc[m][0][q] + bfv;
      float pi = acc[m][1][q] + biv;
      float po = acc[m][2][q] + bov;
      float pc = acc[m][3][q] + bcv;
      float fg = sigmoid_f(pf);
      float ig = sigmoid_f(pi);
      float og = sigmoid_f(po);
      float cg = tanh_f(pc);
      float cold = cell[(size_t)row * NH + n_out];
      float cn = fg * cold + ig * cg;
      float hn = og * tanh_f(cn);
      outH[(size_t)row * NH + n_out] = hn;
      outC[(size_t)row * NH + n_out] = cn;
    }
  }
}

extern "C" void kernel_launch(void* const* d_in, const int* in_sizes, int n_in,
                              void* d_out, int out_size, void* d_ws, size_t ws_size,
                              hipStream_t stream) {
  const float* x    = (const float*)d_in[0];
  const float* h    = (const float*)d_in[1];
  const float* cell = (const float*)d_in[2];
  WPtrs wp; BPtrs bp;
  for (int g = 0; g < 4; ++g) {
    wp.wx[g] = (const float*)d_in[3 + 2 * g];
    bp.bx[g] = (const float*)d_in[4 + 2 * g];
    wp.wh[g] = (const float*)d_in[11 + 2 * g];
    bp.bh[g] = (const float*)d_in[12 + 2 * g];
  }

  char* ws = (char*)d_ws;
  __hip_bfloat16* Acat = (__hip_bfloat16*)ws;
  __hip_bfloat16* Bcat = (__hip_bfloat16*)(ws + (size_t)BATCH * KCAT * 2);
  float* biasc = (float*)(ws + (size_t)BATCH * KCAT * 2 + (size_t)NJ * KCAT * 2);

  float* outH = (float*)d_out;
  float* outC = outH + (size_t)BATCH * NH;

  pack_all<<<8208, 256, 0, stream>>>(x, h, wp, bp, Acat, Bcat, biasc);

  lstm_gemm8<<<256, 512, 0, stream>>>((const unsigned short*)Acat,
                                      (const unsigned short*)Bcat,
                                      biasc, cell, outH, outC);
}